// Round 15
// baseline (31417.752 us; speedup 1.0000x reference)
//
#include <hip/hip_runtime.h>

#define TSEQ 2048
#define NB   32
#define HIDN 256
#define NG   1024   // 4*HID

typedef _Float16 half_t;
typedef _Float16 half2_t __attribute__((ext_vector_type(2)));

__device__ __forceinline__ float fdot2f16(unsigned int a, unsigned int b, float c) {
#if __has_builtin(__builtin_amdgcn_fdot2)
    return __builtin_amdgcn_fdot2(__builtin_bit_cast(half2_t, a),
                                  __builtin_bit_cast(half2_t, b), c, false);
#else
    half2_t x = __builtin_bit_cast(half2_t, a);
    half2_t y = __builtin_bit_cast(half2_t, b);
    return c + (float)x[0] * (float)y[0] + (float)x[1] * (float)y[1];
#endif
}

__device__ __forceinline__ unsigned int packh2(float lo, float hi) {
    half_t l = (half_t)lo, h = (half_t)hi;
    return (unsigned int)__builtin_bit_cast(unsigned short, l) |
           ((unsigned int)__builtin_bit_cast(unsigned short, h) << 16);
}

__device__ __forceinline__ float fast_exp2(float x) {
#if __has_builtin(__builtin_amdgcn_exp2f)
    return __builtin_amdgcn_exp2f(x);
#else
    return exp2f(x);
#endif
}
__device__ __forceinline__ float fast_rcp(float x) {
#if __has_builtin(__builtin_amdgcn_rcpf)
    return __builtin_amdgcn_rcpf(x);
#else
    return 1.0f / x;
#endif
}
__device__ __forceinline__ float sigf(float x) {
    float e = fast_exp2(x * -1.442695041f);
    return fast_rcp(1.0f + e);
}
__device__ __forceinline__ float tanh_fast(float x) {
    float e = fast_exp2(x * 2.885390082f);
    return 1.0f - 2.0f * fast_rcp(e + 1.0f);
}

// keep-alive for VGPR-resident weights (low pressure here, safe per r14 scale)
__device__ __forceinline__ void pin4(uint4& v) {
    asm volatile("" : "+v"(v.x), "+v"(v.y), "+v"(v.z), "+v"(v.w));
}

// AGPR write (volatile: pin + no remat) / read (volatile: no loop-hoist,
// which would recreate the 96-VGPR pressure problem)
#define AWR(aslot, val) \
    asm volatile("v_accvgpr_write_b32 %0, %1" : "=a"(aslot) : "v"(val))
#define ARD(dst, aslot) \
    asm volatile("v_accvgpr_read_b32 %0, %1" : "=v"(dst) : "a"(aslot))

// ---------------------------------------------------------------------------
// K1: pack weights.
//  Wh -> Whp3[r_all*512 + t], r_all = cs*32+kk in [0,64), t in [0,512):
//    u = t&255, hf = t>>8, col = (2*hf+cs)*256 + u, k0 = kk*8.
//    uint4 comp d packs rows (k0+2d, k0+2d+1) of col.
//  Wi -> Wip (xproj_gemm layout, unchanged).
// ---------------------------------------------------------------------------
__global__ void pack_w(const float* __restrict__ Wi, const float* __restrict__ Wh,
                       uint4* __restrict__ Whp3, uint4* __restrict__ Wip) {
    int idx = blockIdx.x * 256 + threadIdx.x;   // 0..65535
    if (idx < 32768) {
        int r_all = idx >> 9, t = idx & 511;
        int u = t & 255, hf = t >> 8;
        int kk = r_all & 31, cs = r_all >> 5;
        int col = (2 * hf + cs) * 256 + u;
        int k0 = kk * 8;
        Whp3[idx] = make_uint4(
            packh2(Wh[(k0 + 0) * NG + col], Wh[(k0 + 1) * NG + col]),
            packh2(Wh[(k0 + 2) * NG + col], Wh[(k0 + 3) * NG + col]),
            packh2(Wh[(k0 + 4) * NG + col], Wh[(k0 + 5) * NG + col]),
            packh2(Wh[(k0 + 6) * NG + col], Wh[(k0 + 7) * NG + col]));
    } else {
        int li = idx & 32767;
        int m4 = li >> 10, tt = li & 1023;
        int col = (tt & 3) * 256 + (tt >> 2);
        int k0 = m4 * 8;
        Wip[li] = make_uint4(
            packh2(Wi[(k0 + 0) * NG + col], Wi[(k0 + 1) * NG + col]),
            packh2(Wi[(k0 + 2) * NG + col], Wi[(k0 + 3) * NG + col]),
            packh2(Wi[(k0 + 4) * NG + col], Wi[(k0 + 5) * NG + col]),
            packh2(Wi[(k0 + 6) * NG + col], Wi[(k0 + 7) * NG + col]));
    }
}

// ---------------------------------------------------------------------------
// K2: x_proj GEMM (unchanged): X [65536][256] fp32 @ Wi -> XP ushort4,
// gate-interleaved f16: half index row*1024 + j*4 + g.
// ---------------------------------------------------------------------------
__global__ __launch_bounds__(1024) void xproj_gemm(
    const float* __restrict__ X, const uint4* __restrict__ Wip,
    ushort4* __restrict__ XP)
{
    __shared__ uint4 atile[32][32];
    const int tid = threadIdx.x;
    const long row0 = (long)blockIdx.x * 32;

    {
        int r = tid >> 5, kc = tid & 31;
        const float4* src = (const float4*)(X + (row0 + r) * 256 + kc * 8);
        float4 f0 = src[0], f1 = src[1];
        atile[r][kc] = make_uint4(packh2(f0.x, f0.y), packh2(f0.z, f0.w),
                                  packh2(f1.x, f1.y), packh2(f1.z, f1.w));
    }
    __syncthreads();

    const int j = tid & 255, rq = tid >> 8;
    float acc[8][4];
#pragma unroll
    for (int r = 0; r < 8; ++r)
#pragma unroll
        for (int g = 0; g < 4; ++g) acc[r][g] = 0.f;

    unsigned off = (unsigned)(j * 4);
#pragma unroll 2
    for (int m4 = 0; m4 < 32; ++m4) {
        uint4 w0 = Wip[off + 0];
        uint4 w1 = Wip[off + 1];
        uint4 w2 = Wip[off + 2];
        uint4 w3 = Wip[off + 3];
#pragma unroll
        for (int rr = 0; rr < 8; ++rr) {
            uint4 av = atile[rq * 8 + rr][m4];
            acc[rr][0] = fdot2f16(w0.x, av.x, acc[rr][0]);
            acc[rr][0] = fdot2f16(w0.y, av.y, acc[rr][0]);
            acc[rr][0] = fdot2f16(w0.z, av.z, acc[rr][0]);
            acc[rr][0] = fdot2f16(w0.w, av.w, acc[rr][0]);
            acc[rr][1] = fdot2f16(w1.x, av.x, acc[rr][1]);
            acc[rr][1] = fdot2f16(w1.y, av.y, acc[rr][1]);
            acc[rr][1] = fdot2f16(w1.z, av.z, acc[rr][1]);
            acc[rr][1] = fdot2f16(w1.w, av.w, acc[rr][1]);
            acc[rr][2] = fdot2f16(w2.x, av.x, acc[rr][2]);
            acc[rr][2] = fdot2f16(w2.y, av.y, acc[rr][2]);
            acc[rr][2] = fdot2f16(w2.z, av.z, acc[rr][2]);
            acc[rr][2] = fdot2f16(w2.w, av.w, acc[rr][2]);
            acc[rr][3] = fdot2f16(w3.x, av.x, acc[rr][3]);
            acc[rr][3] = fdot2f16(w3.y, av.y, acc[rr][3]);
            acc[rr][3] = fdot2f16(w3.z, av.z, acc[rr][3]);
            acc[rr][3] = fdot2f16(w3.w, av.w, acc[rr][3]);
        }
        off += 1024;
    }

#pragma unroll
    for (int rr = 0; rr < 8; ++rr) {
        long row = row0 + rq * 8 + rr;
        XP[row * 256 + j] = make_ushort4(
            __builtin_bit_cast(unsigned short, (half_t)acc[rr][0]),
            __builtin_bit_cast(unsigned short, (half_t)acc[rr][1]),
            __builtin_bit_cast(unsigned short, (half_t)acc[rr][2]),
            __builtin_bit_cast(unsigned short, (half_t)acc[rr][3]));
    }
}

// ---------------------------------------------------------------------------
// K3: persistent recurrence, r13 geometry (proven correct) + AGPR residency.
// 32 WGs (1/batch row), 512 threads. Thread (hf=t>>8, u=t&255) owns gate
// columns 2hf (cs=0) and 2hf+1 (cs=1) of unit u: 64 chunks.
// Residency (measured capacities): kk 0..11 -> AGPR via "a"-asm (96 a-regs,
// allocator-proof: r5/r9 remat, r12 shuffle, r13 spill all defeated VGPR-only
// attempts); kk 12..17 -> VGPR (48 regs, r14-proven scale, pinned);
// kk 18..26 -> LDS (147 KB); kk 27..31 -> streamed from L2 (80 KB/step).
// Cross-half gate exchange via LDS exch + 2 barriers (intra-WG only; r14
// proved cross-WG atomics cost ~8 us/step).
// ---------------------------------------------------------------------------
__global__
__attribute__((amdgpu_flat_work_group_size(512, 512)))
__attribute__((amdgpu_waves_per_eu(2, 2)))
void lstm_rec(
    const uint4* __restrict__ Whp3, const unsigned short* __restrict__ XPh,
    const float* __restrict__ bias, const float* __restrict__ h0,
    const float* __restrict__ c0, float* __restrict__ out)
{
    __shared__ __align__(16) uint4 wlds[18][512];      // 147 KB
    __shared__ __align__(16) uint4 hpair[2][32];       // 2 x 256 f16
    __shared__ __align__(8)  float2 exch[256];         // (g,o) hand-off

    const int t  = threadIdx.x;
    const int b  = blockIdx.x;
    const int u  = t & 255;
    const int hf = t >> 8;

    // kk 0..11 -> AGPRs (dword (kk*2+cs)*4 + d)
    unsigned ag[96];
#pragma unroll
    for (int kk = 0; kk < 12; ++kk) {
#pragma unroll
        for (int cs = 0; cs < 2; ++cs) {
            uint4 v = Whp3[(cs * 32 + kk) * 512 + t];
            const int ai = (kk * 2 + cs) * 4;
            AWR(ag[ai + 0], v.x); AWR(ag[ai + 1], v.y);
            AWR(ag[ai + 2], v.z); AWR(ag[ai + 3], v.w);
        }
    }
    // kk 12..17 -> VGPRs
    uint4 wv[12];
#pragma unroll
    for (int kk = 0; kk < 6; ++kk)
#pragma unroll
        for (int cs = 0; cs < 2; ++cs)
            wv[kk * 2 + cs] = Whp3[(cs * 32 + 12 + kk) * 512 + t];
#pragma unroll
    for (int i = 0; i < 12; ++i) pin4(wv[i]);
    // kk 18..26 -> LDS
#pragma unroll
    for (int kk = 0; kk < 9; ++kk)
#pragma unroll
        for (int cs = 0; cs < 2; ++cs)
            wlds[kk * 2 + cs][t] = Whp3[(cs * 32 + 18 + kk) * 512 + t];

    const float b0 = bias[(2 * hf + 0) * 256 + u];
    const float b1 = bias[(2 * hf + 1) * 256 + u];
    float c_state = (hf == 0) ? c0[b * HIDN + u] : 0.f;
    if (hf == 0) {
        ((unsigned short*)hpair[0])[u] =
            __builtin_bit_cast(unsigned short, (half_t)h0[b * HIDN + u]);
    }
    const char* xpbase = (const char*)(XPh + (long)b * TSEQ * NG)
                       + u * 8 + hf * 4;
    float* ys = out + 2 * NB * HIDN + (long)b * TSEQ * HIDN;
    __syncthreads();

    int buf = 0;
    for (int step = 0; step < TSEQ; ++step) {
        // streamed chunks kk 27..31 (L2-resident), issue first
        uint4 wst[10];
#pragma unroll
        for (int kk = 0; kk < 5; ++kk)
#pragma unroll
            for (int cs = 0; cs < 2; ++cs)
                wst[kk * 2 + cs] = Whp3[(cs * 32 + 27 + kk) * 512 + t];

        unsigned xpw = *(const unsigned*)(xpbase + (long)step * 2048);
        float xpf0 = (float)__builtin_bit_cast(half_t, (unsigned short)(xpw & 0xffff));
        float xpf1 = (float)__builtin_bit_cast(half_t, (unsigned short)(xpw >> 16));

        const uint4* hv4 = hpair[buf];
        float z0a = 0.f, z0b = 0.f, z1a = 0.f, z1b = 0.f;
#pragma unroll
        for (int kk = 0; kk < 32; ++kk) {
            uint4 hv = hv4[kk];
            uint4 w0, w1;
            if (kk < 12) {
                const int a0i = (kk * 2 + 0) * 4, a1i = (kk * 2 + 1) * 4;
                ARD(w0.x, ag[a0i + 0]); ARD(w0.y, ag[a0i + 1]);
                ARD(w0.z, ag[a0i + 2]); ARD(w0.w, ag[a0i + 3]);
                ARD(w1.x, ag[a1i + 0]); ARD(w1.y, ag[a1i + 1]);
                ARD(w1.z, ag[a1i + 2]); ARD(w1.w, ag[a1i + 3]);
            } else if (kk < 18) {
                w0 = wv[(kk - 12) * 2 + 0];
                w1 = wv[(kk - 12) * 2 + 1];
            } else if (kk < 27) {
                w0 = wlds[(kk - 18) * 2 + 0][t];
                w1 = wlds[(kk - 18) * 2 + 1][t];
            } else {
                w0 = wst[(kk - 27) * 2 + 0];
                w1 = wst[(kk - 27) * 2 + 1];
            }
            if ((kk & 1) == 0) {
                z0a = fdot2f16(w0.x, hv.x, z0a); z0a = fdot2f16(w0.y, hv.y, z0a);
                z0a = fdot2f16(w0.z, hv.z, z0a); z0a = fdot2f16(w0.w, hv.w, z0a);
                z1a = fdot2f16(w1.x, hv.x, z1a); z1a = fdot2f16(w1.y, hv.y, z1a);
                z1a = fdot2f16(w1.z, hv.z, z1a); z1a = fdot2f16(w1.w, hv.w, z1a);
            } else {
                z0b = fdot2f16(w0.x, hv.x, z0b); z0b = fdot2f16(w0.y, hv.y, z0b);
                z0b = fdot2f16(w0.z, hv.z, z0b); z0b = fdot2f16(w0.w, hv.w, z0b);
                z1b = fdot2f16(w1.x, hv.x, z1b); z1b = fdot2f16(w1.y, hv.y, z1b);
                z1b = fdot2f16(w1.z, hv.z, z1b); z1b = fdot2f16(w1.w, hv.w, z1b);
            }
        }
        float z0 = (z0a + z0b) + xpf0 + b0;
        float z1 = (z1a + z1b) + xpf1 + b1;

        float a0, a1;
        if (hf == 0) { a0 = sigf(z0);      a1 = sigf(z1); }   // i, f
        else         { a0 = tanh_fast(z0); a1 = sigf(z1); }   // g, o

        if (hf == 1) exch[u] = make_float2(a0, a1);
        __syncthreads();

        if (hf == 0) {
            float2 go = exch[u];                 // (g, o)
            float cn = a1 * c_state + a0 * go.x; // f*c + i*g
            float hn = go.y * tanh_fast(cn);     // o*tanh(c)
            c_state = cn;
            ((unsigned short*)hpair[buf ^ 1])[u] =
                __builtin_bit_cast(unsigned short, (half_t)hn);
            ys[(long)step * HIDN + u] = hn;
            if (step == TSEQ - 1) {
                out[b * HIDN + u] = hn;                  // hT
                out[NB * HIDN + b * HIDN + u] = cn;      // cT
            }
        }
        __syncthreads();
        buf ^= 1;
    }
}

// ---------------------------------------------------------------------------
extern "C" void kernel_launch(void* const* d_in, const int* in_sizes, int n_in,
                              void* d_out, int out_size, void* d_ws, size_t ws_size,
                              hipStream_t stream) {
    const float* X  = (const float*)d_in[0];   // [32][2048][256]
    const float* Wi = (const float*)d_in[1];   // [256][1024]
    const float* Wh = (const float*)d_in[2];   // [256][1024]
    const float* bv = (const float*)d_in[3];   // [1024]
    const float* h0 = (const float*)d_in[4];   // [32][256]
    const float* c0 = (const float*)d_in[5];   // [32][256]
    float* out = (float*)d_out;

    char* ws = (char*)d_ws;
    uint4* Whp3 = (uint4*)(ws);                      // 512 KB
    uint4* Wip  = (uint4*)(ws + (512 << 10));        // 512 KB
    unsigned short* XPh = (unsigned short*)(ws + (1 << 20));  // 128 MB

    pack_w<<<256, 256, 0, stream>>>(Wi, Wh, Whp3, Wip);
    xproj_gemm<<<2048, 1024, 0, stream>>>(X, Wip, (ushort4*)XPh);
    lstm_rec<<<NB, 512, 0, stream>>>(Whp3, XPh, bv, h0, c0, out);
}